// Round 1
// 1116.744 us; speedup vs baseline: 1.0082x; 1.0082x over previous
//
#include <hip/hip_runtime.h>
#include <math.h>

#define B_ 4
#define N_ 500
#define K_ 50
#define D_ 2048
#define IMG_ 224

// ---------------- distance matrix: dist[b][n] = ||q_b - bank_n|| ----------------
__global__ void dist_kernel(const float* __restrict__ x2, const float* __restrict__ f2,
                            float* __restrict__ dist) {
  const int n = blockIdx.x, b = blockIdx.y;
  const float4* q = (const float4*)(x2 + (size_t)b * D_);
  const float4* r = (const float4*)(f2 + (size_t)n * D_);
  float s = 0.f;
#pragma unroll
  for (int c = 0; c < 2; c++) {
    const float4 qa = q[threadIdx.x + c * 256];
    const float4 ra = r[threadIdx.x + c * 256];
    const float d0 = qa.x - ra.x, d1 = qa.y - ra.y;
    const float d2 = qa.z - ra.z, d3 = qa.w - ra.w;
    s += d0 * d0 + d1 * d1 + d2 * d2 + d3 * d3;
  }
  for (int o = 32; o; o >>= 1) s += __shfl_down(s, o);
  __shared__ float part[4];
  const int lane = threadIdx.x & 63, wv = threadIdx.x >> 6;
  if (lane == 0) part[wv] = s;
  __syncthreads();
  if (threadIdx.x == 0)
    dist[b * N_ + n] = sqrtf(part[0] + part[1] + part[2] + part[3]);
}

// ---------------- top-K smallest (one wave per batch) ----------------
__global__ void topk_kernel(const float* __restrict__ dist, int* __restrict__ idx,
                            float* __restrict__ score) {
  const int b = blockIdx.x;
  const int lane = threadIdx.x;  // 64 threads = 1 wave
  float v[8];
  int id[8];
  int cnt = 0;
  for (int n = lane; n < N_; n += 64) { v[cnt] = dist[b * N_ + n]; id[cnt] = n; cnt++; }
  for (int c = cnt; c < 8; c++) { v[c] = INFINITY; id[c] = -1; }
  float ssum = 0.f;
  for (int k = 0; k < K_; k++) {
    float bestv = v[0];
    int besti = 0;
#pragma unroll
    for (int c = 1; c < 8; c++)
      if (v[c] < bestv) { bestv = v[c]; besti = c; }
    // distances are >= 0 so float bits order as uint; low bits = lane (unique -> no ties)
    unsigned long long key =
        ((unsigned long long)__float_as_uint(bestv) << 32) | (unsigned)lane;
    for (int o = 32; o; o >>= 1) {
      unsigned long long other = __shfl_xor(key, o);
      if (other < key) key = other;
    }
    const int wl = (int)(key & 63u);
    const float wvmin = __uint_as_float((unsigned)(key >> 32));
    if (lane == wl) {
      idx[b * K_ + k] = id[besti];
      v[besti] = INFINITY;
    }
    ssum += wvmin;
  }
  if (lane == 0) score[b] = ssum / (float)K_;
}

// ---------------- per-position min over K gathered rows (both scales in one launch) ----------
// 512 threads = 8 waves; wave wv handles k = wv, wv+8, ...; 2-deep pipelined gather loads.
template <int C, int H>
__device__ void mindist_body(const float* __restrict__ f, const float* __restrict__ x,
                             const int* idx_s, float* red, float* __restrict__ m,
                             const int p) {
  const int b = p / (H * H);
  const int hw = p - b * (H * H);
  const int lane = threadIdx.x & 63;
  const int wv = threadIdx.x >> 6;
  constexpr int V = C / 256;  // float4 loads per lane per row
  const float4* xrow = (const float4*)(x + ((size_t)b * H * H + hw) * C);
  float4 xv[V];
#pragma unroll
  for (int i = 0; i < V; i++) xv[i] = xrow[lane + i * 64];
  float best = INFINITY;
  int k = wv;  // wv in [0,8) < K_
  {
    const float4* frow = (const float4*)(f + ((size_t)idx_s[k] * H * H + hw) * C);
    float4 fv[V];
#pragma unroll
    for (int i = 0; i < V; i++) fv[i] = frow[lane + i * 64];
    while (true) {
      const int k2 = k + 8;
      float4 gv[V];
      if (k2 < K_) {
        const float4* grow = (const float4*)(f + ((size_t)idx_s[k2] * H * H + hw) * C);
#pragma unroll
        for (int i = 0; i < V; i++) gv[i] = grow[lane + i * 64];
      }
      float s = 0.f;
#pragma unroll
      for (int i = 0; i < V; i++) {
        const float d0 = fv[i].x - xv[i].x, d1 = fv[i].y - xv[i].y;
        const float d2 = fv[i].z - xv[i].z, d3 = fv[i].w - xv[i].w;
        s += d0 * d0 + d1 * d1 + d2 * d2 + d3 * d3;
      }
#pragma unroll
      for (int o = 32; o; o >>= 1) s += __shfl_down(s, o);
      best = fminf(best, s);  // only lane 0's value is used
      if (k2 >= K_) break;
#pragma unroll
      for (int i = 0; i < V; i++) fv[i] = gv[i];
      k = k2;
    }
  }
  if (lane == 0) red[wv] = best;
  __syncthreads();
  if (threadIdx.x == 0) {
    float r = red[0];
#pragma unroll
    for (int w = 1; w < 8; w++) r = fminf(r, red[w]);
    m[p] = sqrtf(r);
  }
}

__global__ __launch_bounds__(512) void mindist_all(
    const float* __restrict__ f0, const float* __restrict__ x0,
    const float* __restrict__ f1, const float* __restrict__ x1,
    const int* __restrict__ idx, float* __restrict__ m0, float* __restrict__ m1) {
  __shared__ int idx_s[K_];
  __shared__ float red[8];
  const int bid = blockIdx.x;
  const int isF1 = bid >= B_ * 28 * 28;          // uniform per block
  const int p = isF1 ? bid - B_ * 28 * 28 : bid;
  const int b = isF1 ? p / (14 * 14) : p / (28 * 28);
  if (threadIdx.x < K_) idx_s[threadIdx.x] = idx[b * K_ + threadIdx.x];
  __syncthreads();
  if (!isF1)
    mindist_body<512, 28>(f0, x0, idx_s, red, m0, p);
  else
    mindist_body<1024, 14>(f1, x1, idx_s, red, m1, p);
}

// ---------------- fused bilinear upsample + separable gaussian blur ----------------
__device__ inline float bilerp(const float* __restrict__ m, int H, int i, int j) {
  const float scale = (float)H / (float)IMG_;
  float ty = fminf(fmaxf(((float)i + 0.5f) * scale - 0.5f, 0.f), (float)(H - 1));
  float tx = fminf(fmaxf(((float)j + 0.5f) * scale - 0.5f, 0.f), (float)(H - 1));
  const int y0 = (int)ty, x0 = (int)tx;
  const int y1 = y0 + 1 < H ? y0 + 1 : H - 1;
  const int x1 = x0 + 1 < H ? x0 + 1 : H - 1;
  const float wy = ty - (float)y0, wx = tx - (float)x0;
  const float a = m[y0 * H + x0] * (1.f - wx) + m[y0 * H + x1] * wx;
  const float c = m[y1 * H + x0] * (1.f - wx) + m[y1 * H + x1] * wx;
  return a * (1.f - wy) + c * wy;
}

__device__ inline int reflect101(int t) {
  t = t < 0 ? -t : t;
  t = t > IMG_ - 1 ? 2 * (IMG_ - 1) - t : t;
  return t;
}

// one block = 32x32 output tile; upsample recomputed into a 64x64 LDS tile (16 halo),
// then vertical blur -> 32x64 LDS, then horizontal blur -> global.
// gaussian normalization folded into final store (1/sum^2).
__global__ __launch_bounds__(256) void mask_kernel(const float* __restrict__ m0,
                                                   const float* __restrict__ m1,
                                                   float* __restrict__ outm) {
  __shared__ float gk_s[33];
  __shared__ float inv2;
  __shared__ float up_s[64][64];
  __shared__ float tmp_s[32][64];
  const int tid = threadIdx.x;
  const int tx0 = blockIdx.x * 32, ty0 = blockIdx.y * 32, b = blockIdx.z;

  if (tid < 33) {
    const float xx = (float)tid - 16.f;
    gk_s[tid] = expf(-(xx * xx) / 32.f);  // 2*sigma^2 = 32
  }
  __syncthreads();
  if (tid == 0) {
    float s = 0.f;
#pragma unroll
    for (int i = 0; i < 33; i++) s += gk_s[i];
    inv2 = 1.f / (s * s);
  }

  const float* mb0 = m0 + b * 28 * 28;
  const float* mb1 = m1 + b * 14 * 14;
  // fill 64x64 upsampled tile (reflect-101 halo): 16 values per thread
#pragma unroll
  for (int e = tid; e < 64 * 64; e += 256) {
    const int yy = e >> 6, xx = e & 63;
    const int iy = reflect101(ty0 + yy - 16);
    const int ix = reflect101(tx0 + xx - 16);
    const float a0 = bilerp(mb0, 28, iy, ix);
    const float a1 = bilerp(mb1, 14, iy, ix);
    up_s[yy][xx] = 0.5f * (a0 + a1);
  }
  __syncthreads();
  // vertical pass: 32 rows x 64 cols
#pragma unroll
  for (int e = tid; e < 32 * 64; e += 256) {
    const int y = e >> 6, x = e & 63;
    float s = 0.f;
#pragma unroll
    for (int o = 0; o < 33; o++) s += gk_s[o] * up_s[y + o][x];
    tmp_s[y][x] = s;
  }
  __syncthreads();
  // horizontal pass: 32x32 outputs
#pragma unroll
  for (int e = tid; e < 32 * 32; e += 256) {
    const int y = e >> 5, x = e & 31;
    float s = 0.f;
#pragma unroll
    for (int o = 0; o < 33; o++) s += gk_s[o] * tmp_s[y][x + o];
    outm[((size_t)b * IMG_ + (ty0 + y)) * IMG_ + (tx0 + x)] = s * inv2;
  }
}

extern "C" void kernel_launch(void* const* d_in, const int* in_sizes, int n_in,
                              void* d_out, int out_size, void* d_ws, size_t ws_size,
                              hipStream_t stream) {
  const float* x0 = (const float*)d_in[0];  // [4,28,28,512]
  const float* x1 = (const float*)d_in[1];  // [4,14,14,1024]
  const float* x2 = (const float*)d_in[2];  // [4,1,1,2048]
  const float* f0 = (const float*)d_in[3];  // [500,28,28,512]
  const float* f1 = (const float*)d_in[4];  // [500,14,14,1024]
  const float* f2 = (const float*)d_in[5];  // [500,1,1,2048]
  float* out = (float*)d_out;               // [4] score + [4*224*224] mask

  float* ws = (float*)d_ws;
  float* dist = ws;                  // 2000
  int* idxb = (int*)(ws + 2000);     // 200
  float* m0 = ws + 2200;             // 3136
  float* m1 = ws + 5336;             // 784

  dist_kernel<<<dim3(N_, B_), 256, 0, stream>>>(x2, f2, dist);
  topk_kernel<<<B_, 64, 0, stream>>>(dist, idxb, out);  // writes score -> out[0..3]
  mindist_all<<<B_ * 28 * 28 + B_ * 14 * 14, 512, 0, stream>>>(f0, x0, f1, x1, idxb, m0, m1);
  mask_kernel<<<dim3(7, 7, B_), 256, 0, stream>>>(m0, m1, out + B_);
}